// Round 2
// baseline (401.922 us; speedup 1.0000x reference)
//
#include <hip/hip_runtime.h>
#include <math.h>

#define BB 2
#define NN 512
#define SCALEF 0.17677669529663687f  // 1/sqrt(16 + 4*4)

// ================= generic register-blocked GEMM core =================
// C[row0.., ccol..] = A[row0.., k] @ B + bias   (NN: B is [K,N] at col bcol;
// NT: B is [N,K] rows at bcol). 128 threads. K % 16 == 0.
template<int BM,int BN,int TM,int TN,int NTY,int NTX,bool NT,bool ACC>
__device__ __forceinline__ void gemm_core(
    const float* __restrict__ A, int lda,
    const float* __restrict__ Bm, int ldb,
    const float* __restrict__ bias,
    float* __restrict__ C, int ldc,
    int K, int row0, int bcol, int ccol) {
  constexpr int NTH = NTY * NTX;
  __shared__ float As[BM][20];
  __shared__ float Bs[BN][20];
  float acc[TM][TN];
#pragma unroll
  for (int m = 0; m < TM; ++m)
#pragma unroll
    for (int n = 0; n < TN; ++n) acc[m][n] = 0.f;

  const int tid = threadIdx.x;
  const int tx = tid % NTX, ty = tid / NTX;

  for (int k0 = 0; k0 < K; k0 += 16) {
    // stage A tile [BM][16] as float4 granules
#pragma unroll
    for (int i = tid; i < BM * 4; i += NTH) {
      int r = i >> 2, q = i & 3;
      *(float4*)(&As[r][q * 4]) =
          *(const float4*)(A + (long)(row0 + r) * lda + k0 + q * 4);
    }
    if (NT) {
#pragma unroll
      for (int i = tid; i < BN * 4; i += NTH) {
        int c = i >> 2, q = i & 3;
        *(float4*)(&Bs[c][q * 4]) =
            *(const float4*)(Bm + (long)(bcol + c) * ldb + k0 + q * 4);
      }
    } else {
#pragma unroll
      for (int i = tid; i < BN * 16; i += NTH) {
        int kk = i / BN, c = i - kk * BN;
        Bs[c][kk] = Bm[(long)(k0 + kk) * ldb + bcol + c];
      }
    }
    __syncthreads();
#pragma unroll
    for (int kq = 0; kq < 4; ++kq) {
      float4 av[TM], bv[TN];
#pragma unroll
      for (int m = 0; m < TM; ++m)
        av[m] = *(const float4*)(&As[ty + NTY * m][kq * 4]);
#pragma unroll
      for (int n = 0; n < TN; ++n)
        bv[n] = *(const float4*)(&Bs[tx + NTX * n][kq * 4]);
#pragma unroll
      for (int m = 0; m < TM; ++m)
#pragma unroll
        for (int n = 0; n < TN; ++n)
          acc[m][n] += av[m].x * bv[n].x + av[m].y * bv[n].y +
                       av[m].z * bv[n].z + av[m].w * bv[n].w;
    }
    __syncthreads();
  }
#pragma unroll
  for (int m = 0; m < TM; ++m)
#pragma unroll
    for (int n = 0; n < TN; ++n) {
      int r = row0 + ty + NTY * m;
      int c = ccol + tx + NTX * n;
      float v = acc[m][n];
      if (bias) v += bias[tx + NTX * n];
      long idx = (long)r * ldc + c;
      if (ACC) v += C[idx];
      C[idx] = v;
    }
}

// ---------------- fused input projections (4 GEMMs, one launch) ----------------
__global__ __launch_bounds__(128) void ipa_input_proj(
    const float* __restrict__ hidden,
    const float* __restrict__ W_qk, const float* __restrict__ b_qk,
    const float* __restrict__ W_vs, const float* __restrict__ b_vs,
    const float* __restrict__ W_pv, const float* __restrict__ b_pv,
    const float* __restrict__ W_pqk, const float* __restrict__ b_pqk,
    float* __restrict__ QK, float* __restrict__ VVP, float* __restrict__ QP) {
  int t = blockIdx.x;
  const float* W; const float* bias; float* C;
  int ldw, ldc, wcol, ccol;
  if (t < 8)       { W = W_qk;  ldw = 384; bias = b_qk;  wcol = t * 48;        C = QK;  ldc = 384; ccol = wcol; }
  else if (t < 12) { W = W_vs;  ldw = 192; bias = b_vs;  wcol = (t - 8) * 48;  C = VVP; ldc = 480; ccol = wcol; }
  else if (t < 18) { W = W_pv;  ldw = 288; bias = b_pv;  wcol = (t - 12) * 48; C = VVP; ldc = 480; ccol = 192 + wcol; }
  else             { W = W_pqk; ldw = 144; bias = b_pqk; wcol = (t - 18) * 48; C = QP;  ldc = 144; ccol = wcol; }
  gemm_core<64,48,4,6,16,8,false,false>(hidden, 384, W, ldw, bias + wcol,
                                        C, ldc, 384, blockIdx.y * 64, wcol, ccol);
}

// ---------------- scalar attention: ATT += q_s @ k_s^T ----------------
__global__ __launch_bounds__(128) void ipa_qk_nt(
    const float* __restrict__ QK, float* __restrict__ ATT) {
  int b = blockIdx.z;
  const float* A = QK + (long)b * NN * 384;        // q part
  const float* B = QK + (long)b * NN * 384 + 192;  // k part (rows j)
  float* C = ATT + (long)b * NN * NN;
  gemm_core<64,32,4,4,16,8,true,true>(A, 384, B, 384, nullptr,
                                      C, NN, 192, blockIdx.y * 64,
                                      blockIdx.x * 32, blockIdx.x * 32);
}

// ---------------- attn @ [v_s | vp] ----------------
__global__ __launch_bounds__(128) void ipa_pv(
    const float* __restrict__ ATT, const float* __restrict__ VVP,
    float* __restrict__ SRPR) {
  int b = blockIdx.z;
  gemm_core<64,48,4,6,16,8,false,false>(
      ATT + (long)b * NN * NN, NN, VVP + (long)b * NN * 480, 480, nullptr,
      SRPR + (long)b * NN * 480, 480, NN, blockIdx.y * 64,
      blockIdx.x * 48, blockIdx.x * 48);
}

// ---------------- output projections W_so / W_po (fused) ----------------
__global__ __launch_bounds__(128) void ipa_out_projA(
    const float* __restrict__ SRPR,
    const float* __restrict__ W_so, const float* __restrict__ b_so,
    const float* __restrict__ W_po, const float* __restrict__ b_po,
    float* __restrict__ PROJ) {
  int t = blockIdx.x;
  if (t < 8) {
    int wcol = t * 48;
    gemm_core<64,48,4,6,16,8,false,false>(SRPR, 480, W_so, 384, b_so + wcol,
                                          PROJ, 768, 192, blockIdx.y * 64, wcol, wcol);
  } else {
    int wcol = (t - 8) * 48;
    gemm_core<64,48,4,6,16,8,false,false>(SRPR + 192, 480, W_po, 384, b_po + wcol,
                                          PROJ, 768, 288, blockIdx.y * 64, wcol, 384 + wcol);
  }
}

// ---------------- final: out = PROJ @ W_fp + b_fp ----------------
__global__ __launch_bounds__(128) void ipa_final(
    const float* __restrict__ PROJ, const float* __restrict__ W_fp,
    const float* __restrict__ b_fp, float* __restrict__ out_res) {
  int wcol = blockIdx.x * 48;
  gemm_core<64,48,4,6,16,8,false,false>(PROJ, 768, W_fp, 384, b_fp + wcol,
                                        out_res, 384, 768, blockIdx.y * 64, wcol, wcol);
}

// ---------------- per-(token,hp): (n2, 1/sqrt(n2+eps)) ----------------
__global__ __launch_bounds__(256) void point_norms(
    const float* __restrict__ QP, float2* __restrict__ NI) {
  int idx = blockIdx.x * 256 + threadIdx.x;  // token*48 + hp
  if (idx >= BB * NN * 48) return;
  int token = idx / 48, hp = idx - token * 48;
  const float* p = QP + (long)token * 144 + hp * 3;
  float n2 = p[0] * p[0] + p[1] * p[1] + p[2] * p[2];
  float inv = __frsqrt_rn(n2 + 1e-12f);
  NI[idx] = make_float2(n2, inv);
}

// ---------------- point term -> ATT (pure write), 32x32 tile, 2x2/thread ----------------
#define P_LD 145
__global__ __launch_bounds__(256) void point_logits(
    const float* __restrict__ QP, const float2* __restrict__ NI,
    float* __restrict__ ATT) {
  __shared__ float Pi[32][P_LD];
  __shared__ float Pj[32][P_LD];
  __shared__ float2 NIi[32][49];
  __shared__ float2 NIj[32][49];
  const int b = blockIdx.z;
  const int i0 = blockIdx.y * 32, j0 = blockIdx.x * 32;
  const int tid = threadIdx.x;
  for (int idx = tid; idx < 32 * 144; idx += 256) {
    int r = idx / 144, c = idx - r * 144;
    Pi[r][c] = QP[((long)(b * NN + i0 + r)) * 144 + c];
    Pj[r][c] = QP[((long)(b * NN + j0 + r)) * 144 + c];
  }
  for (int idx = tid; idx < 32 * 48; idx += 256) {
    int r = idx / 48, c = idx - r * 48;
    NIi[r][c] = NI[((long)(b * NN + i0 + r)) * 48 + c];
    NIj[r][c] = NI[((long)(b * NN + j0 + r)) * 48 + c];
  }
  __syncthreads();
  const int ti = tid >> 4, tj = tid & 15;
  float acc[2][2] = {{0.f, 0.f}, {0.f, 0.f}};
  const float* pi0 = Pi[2 * ti];
  const float* pi1 = Pi[2 * ti + 1];
  const float* pj0 = Pj[2 * tj];
  const float* pj1 = Pj[2 * tj + 1];
#pragma unroll 4
  for (int hp = 0; hp < 48; ++hp) {
    float ax0 = pi0[hp * 3], ay0 = pi0[hp * 3 + 1], az0 = pi0[hp * 3 + 2];
    float ax1 = pi1[hp * 3], ay1 = pi1[hp * 3 + 1], az1 = pi1[hp * 3 + 2];
    float bx0 = pj0[hp * 3], by0 = pj0[hp * 3 + 1], bz0 = pj0[hp * 3 + 2];
    float bx1 = pj1[hp * 3], by1 = pj1[hp * 3 + 1], bz1 = pj1[hp * 3 + 2];
    float2 ni0 = NIi[2 * ti][hp], ni1 = NIi[2 * ti + 1][hp];
    float2 nj0 = NIj[2 * tj][hp], nj1 = NIj[2 * tj + 1][hp];
#pragma unroll
    for (int di = 0; di < 2; ++di) {
      float ax = di ? ax1 : ax0, ay = di ? ay1 : ay0, az = di ? az1 : az0;
      float2 ni = di ? ni1 : ni0;
#pragma unroll
      for (int dj = 0; dj < 2; ++dj) {
        float bx = dj ? bx1 : bx0, by = dj ? by1 : by0, bz = dj ? bz1 : bz0;
        float2 nj = dj ? nj1 : nj0;
        float dot = ax * bx + ay * by + az * bz;
        float d2 = fmaxf(fmaf(-2.f, dot, ni.x + nj.x), 0.f) + 1e-12f;
        float dist = d2 * __frsqrt_rn(d2);
        acc[di][dj] += dist + dot * (ni.y * nj.y);
      }
    }
  }
  float* Cb = ATT + (long)b * NN * NN;
#pragma unroll
  for (int di = 0; di < 2; ++di)
#pragma unroll
    for (int dj = 0; dj < 2; ++dj)
      Cb[(long)(i0 + 2 * ti + di) * NN + (j0 + 2 * tj + dj)] = acc[di][dj];
}

// ---------------- row softmax (applies SCALE) ----------------
__global__ __launch_bounds__(256) void softmax_kernel(float* __restrict__ ATT) {
  int row = blockIdx.x;
  float* p = ATT + (long)row * NN;
  int tid = threadIdx.x;
  float v0 = p[tid] * SCALEF, v1 = p[tid + 256] * SCALEF;
  __shared__ float red[256];
  red[tid] = fmaxf(v0, v1);
  __syncthreads();
  for (int s = 128; s > 0; s >>= 1) {
    if (tid < s) red[tid] = fmaxf(red[tid], red[tid + s]);
    __syncthreads();
  }
  float rowmax = red[0];
  __syncthreads();
  float e0 = __expf(v0 - rowmax), e1 = __expf(v1 - rowmax);
  red[tid] = e0 + e1;
  __syncthreads();
  for (int s = 128; s > 0; s >>= 1) {
    if (tid < s) red[tid] += red[tid + s];
    __syncthreads();
  }
  float inv = 1.0f / red[0];
  p[tid] = e0 * inv;
  p[tid + 256] = e1 * inv;
}

// ---------------- delta_xyz ----------------
__global__ __launch_bounds__(128) void delta_kernel(
    const float* __restrict__ PROJ, const float* __restrict__ xyz,
    float* __restrict__ out2) {
  int token = blockIdx.x;
  int t = threadIdx.x;
  const float* pp = PROJ + (long)token * 768 + 384 + 3 * t;
  __shared__ float sx[128], sy[128], sz[128];
  sx[t] = pp[0]; sy[t] = pp[1]; sz[t] = pp[2];
  __syncthreads();
  for (int s = 64; s > 0; s >>= 1) {
    if (t < s) { sx[t] += sx[t + s]; sy[t] += sy[t + s]; sz[t] += sz[t + s]; }
    __syncthreads();
  }
  if (t == 0) {
    out2[(long)token * 3 + 0] = xyz[(long)token * 3 + 0] + sx[0] * (1.0f / 128.f);
    out2[(long)token * 3 + 1] = xyz[(long)token * 3 + 1] + sy[0] * (1.0f / 128.f);
    out2[(long)token * 3 + 2] = xyz[(long)token * 3 + 2] + sz[0] * (1.0f / 128.f);
  }
}

extern "C" void kernel_launch(void* const* d_in, const int* in_sizes, int n_in,
                              void* d_out, int out_size, void* d_ws, size_t ws_size,
                              hipStream_t stream) {
  const float* hidden = (const float*)d_in[0];
  const float* xyz   = (const float*)d_in[1];
  const float* W_qk  = (const float*)d_in[2];
  const float* b_qk  = (const float*)d_in[3];
  const float* W_vs  = (const float*)d_in[4];
  const float* b_vs  = (const float*)d_in[5];
  const float* W_so  = (const float*)d_in[6];
  const float* b_so  = (const float*)d_in[7];
  const float* W_pqk = (const float*)d_in[8];
  const float* b_pqk = (const float*)d_in[9];
  const float* W_pv  = (const float*)d_in[10];
  const float* b_pv  = (const float*)d_in[11];
  const float* W_po  = (const float*)d_in[12];
  const float* b_po  = (const float*)d_in[13];
  const float* W_fp  = (const float*)d_in[14];
  const float* b_fp  = (const float*)d_in[15];

  float* out_res = (float*)d_out;                  // [B,N,384]
  float* out_xyz = out_res + (long)BB * NN * 384;  // [B,N,3]

  float* ws   = (float*)d_ws;
  float* QK   = ws;                        // [1024,384]
  float* VVP  = QK  + 1024L * 384;         // [1024,480]
  float* QP   = VVP + 1024L * 480;         // [1024,144]
  float* NIb  = QP  + 1024L * 144;         // [1024,48] float2
  float* ATT  = NIb + 1024L * 96;          // [2,512,512]
  float* SRPR = ATT + 2L * 512 * 512;      // [1024,480]
  float* PROJ = SRPR+ 1024L * 480;         // [1024,768]

  ipa_input_proj<<<dim3(21, 16), 128, 0, stream>>>(
      hidden, W_qk, b_qk, W_vs, b_vs, W_pv, b_pv, W_pqk, b_pqk, QK, VVP, QP);
  point_norms<<<192, 256, 0, stream>>>(QP, (float2*)NIb);
  point_logits<<<dim3(16, 16, 2), 256, 0, stream>>>(QP, (const float2*)NIb, ATT);
  ipa_qk_nt<<<dim3(16, 8, 2), 128, 0, stream>>>(QK, ATT);
  softmax_kernel<<<1024, 256, 0, stream>>>(ATT);
  ipa_pv<<<dim3(10, 8, 2), 128, 0, stream>>>(ATT, VVP, SRPR);
  ipa_out_projA<<<dim3(16, 16), 128, 0, stream>>>(SRPR, W_so, b_so, W_po, b_po, PROJ);
  ipa_final<<<dim3(8, 16), 128, 0, stream>>>(PROJ, W_fp, b_fp, out_res);
  delta_kernel<<<1024, 128, 0, stream>>>(PROJ, xyz, out_xyz);
}

// Round 3
// 118.639 us; speedup vs baseline: 3.3878x; 3.3878x over previous
//
#include <hip/hip_runtime.h>
#include <math.h>

typedef unsigned short u16;
typedef __attribute__((ext_vector_type(8))) short bf16x8;
typedef __attribute__((ext_vector_type(4))) float f32x4;

#define BB 2
#define NN 512
#define SCALEF 0.17677669529663687f  // 1/sqrt(16 + 4*4)

__device__ __forceinline__ u16 f2bf(float x) {
  union { float f; unsigned u; } c; c.f = x;
  unsigned r = (c.u + 0x7FFFu + ((c.u >> 16) & 1u)) >> 16;
  return (u16)r;
}
__device__ __forceinline__ float bf2f(u16 h) {
  union { unsigned u; float f; } c; c.u = ((unsigned)h) << 16;
  return c.f;
}

// ================= MFMA GEMM core (compensated bf16x3) =================
// C[64 x 16*NF] tile at (row0, col0). A[M,K] rows (hi/lo), B^T[N,K] rows
// (NT mode) or B[K,N] (BTRANS mode, transpose-staged). 256 threads = 4 waves,
// wave w owns rows row0+16w..+15, all NF col-frags. K % 32 == 0.
template<int NF, bool BTRANS>
__device__ __forceinline__ void mfma_core(
    const u16* __restrict__ Ahi, const u16* __restrict__ Alo, int lda,
    const u16* __restrict__ Bhi, const u16* __restrict__ Blo, int ldb,
    int K, int row0, int col0, f32x4* acc) {
  __shared__ u16 Ah[64][40], Al[64][40];
  __shared__ u16 Bh[16 * NF][40], Bl[16 * NF][40];
  const int tid = threadIdx.x;
  const int lane = tid & 63, wid = tid >> 6;
  const int rr = lane & 15, kg = lane >> 4;

  for (int k0 = 0; k0 < K; k0 += 32) {
    {
      int r = tid >> 2, p = tid & 3;
      const uint4* sh = (const uint4*)(Ahi + (size_t)(row0 + r) * lda + k0 + p * 8);
      const uint4* sl = (const uint4*)(Alo + (size_t)(row0 + r) * lda + k0 + p * 8);
      *(uint4*)&Ah[r][p * 8] = *sh;
      *(uint4*)&Al[r][p * 8] = *sl;
    }
    if (!BTRANS) {
      if (NF == 4 || tid < 16 * NF * 4) {
        int r = tid >> 2, p = tid & 3;
        const uint4* sh = (const uint4*)(Bhi + (size_t)(col0 + r) * ldb + k0 + p * 8);
        const uint4* sl = (const uint4*)(Blo + (size_t)(col0 + r) * ldb + k0 + p * 8);
        *(uint4*)&Bh[r][p * 8] = *sh;
        *(uint4*)&Bl[r][p * 8] = *sl;
      }
    } else {
      for (int t = tid; t < 16 * NF * 16; t += 256) {
        int n = t >> 4, u = t & 15;
        const u16* sh = Bhi + (size_t)(k0 + 2 * u) * ldb + col0 + n;
        const u16* sl = Blo + (size_t)(k0 + 2 * u) * ldb + col0 + n;
        *(unsigned*)&Bh[n][2 * u] = (unsigned)sh[0] | ((unsigned)sh[ldb] << 16);
        *(unsigned*)&Bl[n][2 * u] = (unsigned)sl[0] | ((unsigned)sl[ldb] << 16);
      }
    }
    __syncthreads();
    bf16x8 ah = *(const bf16x8*)&Ah[wid * 16 + rr][kg * 8];
    bf16x8 al = *(const bf16x8*)&Al[wid * 16 + rr][kg * 8];
#pragma unroll
    for (int f = 0; f < NF; ++f) {
      bf16x8 bh = *(const bf16x8*)&Bh[f * 16 + rr][kg * 8];
      bf16x8 bl = *(const bf16x8*)&Bl[f * 16 + rr][kg * 8];
      acc[f] = __builtin_amdgcn_mfma_f32_16x16x32_bf16(ah, bh, acc[f], 0, 0, 0);
      acc[f] = __builtin_amdgcn_mfma_f32_16x16x32_bf16(ah, bl, acc[f], 0, 0, 0);
      acc[f] = __builtin_amdgcn_mfma_f32_16x16x32_bf16(al, bh, acc[f], 0, 0, 0);
    }
    __syncthreads();
  }
}

// ---------------- prep: transpose+split weights, split hidden, zero-pad WOPT ----------------
__global__ __launch_bounds__(256) void prep_kernel(
    const float* __restrict__ hidden,
    const float* __restrict__ W_qk, const float* __restrict__ W_vs,
    const float* __restrict__ W_pv, const float* __restrict__ W_pqk,
    const float* __restrict__ W_so, const float* __restrict__ W_po,
    const float* __restrict__ W_fp,
    u16* Hhi, u16* Hlo, u16* WINh, u16* WINl,
    u16* WOPh, u16* WOPl, u16* WFPh, u16* WFPl) {
  const int bid = blockIdx.x, tid = threadIdx.x;
  if (bid < 852) {
    // transpose jobs: src [K][N] -> dst[nOff+n][kOff+k] (hi/lo bf16)
    const float* src; u16 *dh, *dl;
    int Ns, dld, nOff, kOff, tn, lt;
    if (bid < 144)      { src = W_qk;  Ns = 384; dh = WINh; dl = WINl; dld = 384; nOff = 0;   kOff = 0;   tn = 12; lt = bid; }
    else if (bid < 216) { src = W_vs;  Ns = 192; dh = WINh; dl = WINl; dld = 384; nOff = 384; kOff = 0;   tn = 6;  lt = bid - 144; }
    else if (bid < 324) { src = W_pv;  Ns = 288; dh = WINh; dl = WINl; dld = 384; nOff = 576; kOff = 0;   tn = 9;  lt = bid - 216; }
    else if (bid < 384) { src = W_pqk; Ns = 144; dh = WINh; dl = WINl; dld = 384; nOff = 864; kOff = 0;   tn = 5;  lt = bid - 324; }
    else if (bid < 456) { src = W_so;  Ns = 384; dh = WOPh; dl = WOPl; dld = 480; nOff = 0;   kOff = 0;   tn = 12; lt = bid - 384; }
    else if (bid < 564) { src = W_po;  Ns = 384; dh = WOPh; dl = WOPl; dld = 480; nOff = 384; kOff = 192; tn = 12; lt = bid - 456; }
    else                { src = W_fp;  Ns = 384; dh = WFPh; dl = WFPl; dld = 768; nOff = 0;   kOff = 0;   tn = 12; lt = bid - 564; }
    int k0 = (lt / tn) * 32, n0 = (lt % tn) * 32;
    __shared__ float T[32][33];
    int ty = tid >> 5, tx = tid & 31;
    for (int r = ty; r < 32; r += 8) {
      int gn = n0 + tx;
      T[r][tx] = (gn < Ns) ? src[(size_t)(k0 + r) * Ns + gn] : 0.f;
    }
    __syncthreads();
    for (int r = ty; r < 32; r += 8) {
      int gn = n0 + r;
      if (gn < Ns) {
        float v = T[tx][r];
        u16 hi = f2bf(v), lo = f2bf(v - bf2f(hi));
        size_t idx = (size_t)(nOff + gn) * dld + kOff + k0 + tx;
        dh[idx] = hi; dl[idx] = lo;
      }
    }
  } else if (bid < 916) {
    // hidden split: 64 blocks x 1536 float4
    int base = (bid - 852) * 1536;
    for (int u = tid; u < 1536; u += 256) {
      float4 v = ((const float4*)hidden)[base + u];
      u16 h0 = f2bf(v.x), h1 = f2bf(v.y), h2 = f2bf(v.z), h3 = f2bf(v.w);
      u16 l0 = f2bf(v.x - bf2f(h0)), l1 = f2bf(v.y - bf2f(h1));
      u16 l2 = f2bf(v.z - bf2f(h2)), l3 = f2bf(v.w - bf2f(h3));
      ((ushort4*)Hhi)[base + u] = make_ushort4(h0, h1, h2, h3);
      ((ushort4*)Hlo)[base + u] = make_ushort4(l0, l1, l2, l3);
    }
  } else {
    // zero-fill WOPT complement rects (uint4 granules)
    uint4 z = make_uint4(0u, 0u, 0u, 0u);
    int blk = bid - 916;
    for (int i = tid; i < 1440; i += 256) {
      int unit = blk * 1440 + i;          // 0..46079
      int buf = unit / 23040;
      int r = unit - buf * 23040;
      uint4* W = buf ? (uint4*)WOPl : (uint4*)WOPh;
      if (r < 13824) {                    // rows 0..383, k 192..479
        int row = r / 36, c = r - row * 36;
        W[row * 60 + 24 + c] = z;
      } else {                            // rows 384..767, k 0..191
        r -= 13824;
        int row = 384 + r / 24, c = r - (r / 24) * 24;
        W[row * 60 + c] = z;
      }
    }
  }
}

// ---------------- input projections: [q|k|v|vp|pqk] = hidden @ WIN^T ----------------
__global__ __launch_bounds__(256) void k_input(
    const u16* __restrict__ Hhi, const u16* __restrict__ Hlo,
    const u16* __restrict__ WINh, const u16* __restrict__ WINl,
    const float* __restrict__ b_qk, const float* __restrict__ b_vs,
    const float* __restrict__ b_pv, const float* __restrict__ b_pqk,
    u16* QKh, u16* QKl, u16* VVh, u16* VVl, float* QPf) {
  f32x4 acc[3];
#pragma unroll
  for (int f = 0; f < 3; ++f) { acc[f][0] = 0.f; acc[f][1] = 0.f; acc[f][2] = 0.f; acc[f][3] = 0.f; }
  int row0 = blockIdx.y * 64, col0 = blockIdx.x * 48;
  mfma_core<3, false>(Hhi, Hlo, 384, WINh, WINl, 384, 384, row0, col0, acc);
  int lane = threadIdx.x & 63, wid = threadIdx.x >> 6;
  int rbase = row0 + wid * 16 + (lane >> 4) * 4;
#pragma unroll
  for (int f = 0; f < 3; ++f) {
    int n0 = col0 + f * 16;
    int n = n0 + (lane & 15);
    float bias = (n0 < 384) ? b_qk[n]
               : (n0 < 576) ? b_vs[n - 384]
               : (n0 < 864) ? b_pv[n - 576] : b_pqk[n - 864];
#pragma unroll
    for (int r = 0; r < 4; ++r) {
      float v = acc[f][r] + bias;
      int row = rbase + r;
      if (n0 < 384) {
        u16 hi = f2bf(v);
        QKh[(size_t)row * 384 + n] = hi;
        QKl[(size_t)row * 384 + n] = f2bf(v - bf2f(hi));
      } else if (n0 < 864) {
        int c = n - 384;
        u16 hi = f2bf(v);
        VVh[(size_t)row * 480 + c] = hi;
        VVl[(size_t)row * 480 + c] = f2bf(v - bf2f(hi));
      } else {
        QPf[(size_t)row * 144 + (n - 864)] = v;
      }
    }
  }
}

// ---------------- scalar attention: ATTf += q @ k^T ----------------
__global__ __launch_bounds__(256) void k_qk(
    const u16* __restrict__ QKh, const u16* __restrict__ QKl,
    float* __restrict__ ATTf) {
  f32x4 acc[4];
#pragma unroll
  for (int f = 0; f < 4; ++f) { acc[f][0] = 0.f; acc[f][1] = 0.f; acc[f][2] = 0.f; acc[f][3] = 0.f; }
  int b = blockIdx.z;
  int row0 = blockIdx.y * 64, col0 = blockIdx.x * 64;
  const u16* Ah = QKh + (size_t)b * NN * 384;
  const u16* Al = QKl + (size_t)b * NN * 384;
  mfma_core<4, false>(Ah, Al, 384, Ah + 192, Al + 192, 384, 192, row0, col0, acc);
  float* C = ATTf + (size_t)b * NN * NN;
  int lane = threadIdx.x & 63, wid = threadIdx.x >> 6;
  int rbase = row0 + wid * 16 + (lane >> 4) * 4;
#pragma unroll
  for (int f = 0; f < 4; ++f) {
    int n = col0 + f * 16 + (lane & 15);
#pragma unroll
    for (int r = 0; r < 4; ++r) {
      size_t idx = (size_t)(rbase + r) * NN + n;
      C[idx] += acc[f][r];
    }
  }
}

// ---------------- PV: SRPR = attn @ [v|vp] (B in [K][N], transpose-staged) ----------------
__global__ __launch_bounds__(256) void k_pv(
    const u16* __restrict__ ATBh, const u16* __restrict__ ATBl,
    const u16* __restrict__ VVh, const u16* __restrict__ VVl,
    u16* SRh, u16* SRl) {
  f32x4 acc[3];
#pragma unroll
  for (int f = 0; f < 3; ++f) { acc[f][0] = 0.f; acc[f][1] = 0.f; acc[f][2] = 0.f; acc[f][3] = 0.f; }
  int b = blockIdx.z;
  int row0 = blockIdx.y * 64, col0 = blockIdx.x * 48;
  mfma_core<3, true>(ATBh + (size_t)b * NN * NN, ATBl + (size_t)b * NN * NN, NN,
                     VVh + (size_t)b * NN * 480, VVl + (size_t)b * NN * 480, 480,
                     NN, row0, col0, acc);
  int lane = threadIdx.x & 63, wid = threadIdx.x >> 6;
  int rbase = row0 + wid * 16 + (lane >> 4) * 4;
  u16* outh = SRh + (size_t)b * NN * 480;
  u16* outl = SRl + (size_t)b * NN * 480;
#pragma unroll
  for (int f = 0; f < 3; ++f) {
    int n = col0 + f * 16 + (lane & 15);
#pragma unroll
    for (int r = 0; r < 4; ++r) {
      float v = acc[f][r];
      u16 hi = f2bf(v);
      outh[(size_t)(rbase + r) * 480 + n] = hi;
      outl[(size_t)(rbase + r) * 480 + n] = f2bf(v - bf2f(hi));
    }
  }
}

// ---------------- output projections: PROJ = SRPR @ WOPT^T (block-diag) ----------------
__global__ __launch_bounds__(256) void k_outproj(
    const u16* __restrict__ SRh, const u16* __restrict__ SRl,
    const u16* __restrict__ WOPh, const u16* __restrict__ WOPl,
    const float* __restrict__ b_so, const float* __restrict__ b_po,
    u16* PRh, u16* PRl) {
  f32x4 acc[3];
#pragma unroll
  for (int f = 0; f < 3; ++f) { acc[f][0] = 0.f; acc[f][1] = 0.f; acc[f][2] = 0.f; acc[f][3] = 0.f; }
  int row0 = blockIdx.y * 64, col0 = blockIdx.x * 48;
  mfma_core<3, false>(SRh, SRl, 480, WOPh, WOPl, 480, 480, row0, col0, acc);
  int lane = threadIdx.x & 63, wid = threadIdx.x >> 6;
  int rbase = row0 + wid * 16 + (lane >> 4) * 4;
#pragma unroll
  for (int f = 0; f < 3; ++f) {
    int n = col0 + f * 16 + (lane & 15);
    float bias = (n < 384) ? b_so[n] : b_po[n - 384];
#pragma unroll
    for (int r = 0; r < 4; ++r) {
      float v = acc[f][r] + bias;
      u16 hi = f2bf(v);
      PRh[(size_t)(rbase + r) * 768 + n] = hi;
      PRl[(size_t)(rbase + r) * 768 + n] = f2bf(v - bf2f(hi));
    }
  }
}

// ---------------- final: out = PROJ @ WFP^T + b_fp ----------------
__global__ __launch_bounds__(256) void k_final(
    const u16* __restrict__ PRh, const u16* __restrict__ PRl,
    const u16* __restrict__ WFPh, const u16* __restrict__ WFPl,
    const float* __restrict__ b_fp, float* __restrict__ out_res) {
  f32x4 acc[3];
#pragma unroll
  for (int f = 0; f < 3; ++f) { acc[f][0] = 0.f; acc[f][1] = 0.f; acc[f][2] = 0.f; acc[f][3] = 0.f; }
  int row0 = blockIdx.y * 64, col0 = blockIdx.x * 48;
  mfma_core<3, false>(PRh, PRl, 768, WFPh, WFPl, 768, 768, row0, col0, acc);
  int lane = threadIdx.x & 63, wid = threadIdx.x >> 6;
  int rbase = row0 + wid * 16 + (lane >> 4) * 4;
#pragma unroll
  for (int f = 0; f < 3; ++f) {
    int n = col0 + f * 16 + (lane & 15);
#pragma unroll
    for (int r = 0; r < 4; ++r)
      out_res[(size_t)(rbase + r) * 384 + n] = acc[f][r] + b_fp[n];
  }
}

// ---------------- point term (f32): writes ATTf ----------------
#define PROW 244  // 48*float4(x,y,z,n2) + 48*inv + 4 pad
__global__ __launch_bounds__(256) void point_logits(
    const float* __restrict__ QP, float* __restrict__ ATTf) {
  __shared__ float Pi[32][PROW];
  __shared__ float Pj[32][PROW];
  const int b = blockIdx.z;
  const int i0 = blockIdx.y * 32, j0 = blockIdx.x * 32;
  const int tid = threadIdx.x;
  for (int u = tid; u < 3072; u += 256) {
    int side = u / 1536;
    int rem = u - side * 1536;
    int row = rem / 48, hp = rem - row * 48;
    int grow = b * NN + (side ? j0 : i0) + row;
    const float* p = QP + (size_t)grow * 144 + hp * 3;
    float x = p[0], y = p[1], z = p[2];
    float n2 = x * x + y * y + z * z;
    float inv = __frsqrt_rn(n2 + 1e-12f);
    float* dst = side ? &Pj[row][0] : &Pi[row][0];
    ((float4*)dst)[hp] = make_float4(x, y, z, n2);
    dst[192 + hp] = inv;
  }
  __syncthreads();
  const int tj = tid & 15, ti = tid >> 4;
  float acc[2][2] = {{0.f, 0.f}, {0.f, 0.f}};
  const float4* A0 = (const float4*)&Pi[ti][0];
  const float4* A1 = (const float4*)&Pi[ti + 16][0];
  const float4* B0 = (const float4*)&Pj[tj][0];
  const float4* B1 = (const float4*)&Pj[tj + 16][0];
  const float* iA0 = &Pi[ti][192];
  const float* iA1 = &Pi[ti + 16][192];
  const float* iB0 = &Pj[tj][192];
  const float* iB1 = &Pj[tj + 16][192];
#pragma unroll 4
  for (int hp = 0; hp < 48; ++hp) {
    float4 a0 = A0[hp], a1 = A1[hp], b0 = B0[hp], b1 = B1[hp];
    float va0 = iA0[hp], va1 = iA1[hp], vb0 = iB0[hp], vb1 = iB1[hp];
#pragma unroll
    for (int di = 0; di < 2; ++di) {
      float4 a = di ? a1 : a0;
      float iv = di ? va1 : va0;
#pragma unroll
      for (int dj = 0; dj < 2; ++dj) {
        float4 bb = dj ? b1 : b0;
        float jv = dj ? vb1 : vb0;
        float dot = a.x * bb.x + a.y * bb.y + a.z * bb.z;
        float d2 = fmaxf(fmaf(-2.f, dot, a.w + bb.w), 0.f) + 1e-12f;
        float dist = d2 * __frsqrt_rn(d2);
        acc[di][dj] += dist + dot * (iv * jv);
      }
    }
  }
  float* C = ATTf + (size_t)b * NN * NN;
  C[(size_t)(i0 + ti) * NN + j0 + tj] = acc[0][0];
  C[(size_t)(i0 + ti) * NN + j0 + tj + 16] = acc[0][1];
  C[(size_t)(i0 + ti + 16) * NN + j0 + tj] = acc[1][0];
  C[(size_t)(i0 + ti + 16) * NN + j0 + tj + 16] = acc[1][1];
}

// ---------------- softmax (applies SCALE), writes hi/lo bf16 ----------------
__global__ __launch_bounds__(256) void softmax_kernel(
    const float* __restrict__ ATTf, u16* __restrict__ ATBh, u16* __restrict__ ATBl) {
  int row = blockIdx.x;
  const float* p = ATTf + (size_t)row * NN;
  int tid = threadIdx.x;
  float v0 = p[tid] * SCALEF, v1 = p[tid + 256] * SCALEF;
  __shared__ float red[256];
  red[tid] = fmaxf(v0, v1);
  __syncthreads();
  for (int s = 128; s > 0; s >>= 1) {
    if (tid < s) red[tid] = fmaxf(red[tid], red[tid + s]);
    __syncthreads();
  }
  float rowmax = red[0];
  __syncthreads();
  float e0 = __expf(v0 - rowmax), e1 = __expf(v1 - rowmax);
  red[tid] = e0 + e1;
  __syncthreads();
  for (int s = 128; s > 0; s >>= 1) {
    if (tid < s) red[tid] += red[tid + s];
    __syncthreads();
  }
  float inv = 1.0f / red[0];
  float w0 = e0 * inv, w1 = e1 * inv;
  u16 h0 = f2bf(w0), h1 = f2bf(w1);
  ATBh[(size_t)row * NN + tid] = h0;
  ATBh[(size_t)row * NN + tid + 256] = h1;
  ATBl[(size_t)row * NN + tid] = f2bf(w0 - bf2f(h0));
  ATBl[(size_t)row * NN + tid + 256] = f2bf(w1 - bf2f(h1));
}

// ---------------- delta_xyz ----------------
__global__ __launch_bounds__(128) void delta_kernel(
    const u16* __restrict__ PRh, const u16* __restrict__ PRl,
    const float* __restrict__ xyz, float* __restrict__ out2) {
  int token = blockIdx.x;
  int t = threadIdx.x;
  const u16* ph = PRh + (size_t)token * 768 + 384 + 3 * t;
  const u16* pl = PRl + (size_t)token * 768 + 384 + 3 * t;
  __shared__ float sx[128], sy[128], sz[128];
  sx[t] = bf2f(ph[0]) + bf2f(pl[0]);
  sy[t] = bf2f(ph[1]) + bf2f(pl[1]);
  sz[t] = bf2f(ph[2]) + bf2f(pl[2]);
  __syncthreads();
  for (int s = 64; s > 0; s >>= 1) {
    if (t < s) { sx[t] += sx[t + s]; sy[t] += sy[t + s]; sz[t] += sz[t + s]; }
    __syncthreads();
  }
  if (t == 0) {
    out2[(size_t)token * 3 + 0] = xyz[(size_t)token * 3 + 0] + sx[0] * (1.0f / 128.f);
    out2[(size_t)token * 3 + 1] = xyz[(size_t)token * 3 + 1] + sy[0] * (1.0f / 128.f);
    out2[(size_t)token * 3 + 2] = xyz[(size_t)token * 3 + 2] + sz[0] * (1.0f / 128.f);
  }
}

extern "C" void kernel_launch(void* const* d_in, const int* in_sizes, int n_in,
                              void* d_out, int out_size, void* d_ws, size_t ws_size,
                              hipStream_t stream) {
  const float* hidden = (const float*)d_in[0];
  const float* xyz   = (const float*)d_in[1];
  const float* W_qk  = (const float*)d_in[2];
  const float* b_qk  = (const float*)d_in[3];
  const float* W_vs  = (const float*)d_in[4];
  const float* b_vs  = (const float*)d_in[5];
  const float* W_so  = (const float*)d_in[6];
  const float* b_so  = (const float*)d_in[7];
  const float* W_pqk = (const float*)d_in[8];
  const float* b_pqk = (const float*)d_in[9];
  const float* W_pv  = (const float*)d_in[10];
  const float* b_pv  = (const float*)d_in[11];
  const float* W_po  = (const float*)d_in[12];
  const float* b_po  = (const float*)d_in[13];
  const float* W_fp  = (const float*)d_in[14];
  const float* b_fp  = (const float*)d_in[15];

  float* out_res = (float*)d_out;                  // [B,N,384]
  float* out_xyz = out_res + (size_t)BB * NN * 384;

  u16* Hhi  = (u16*)d_ws;                 // 1024*384
  u16* Hlo  = Hhi  + 393216;
  u16* WINh = Hlo  + 393216;              // 1008*384
  u16* WINl = WINh + 387072;
  u16* WOPh = WINl + 387072;              // 768*480
  u16* WOPl = WOPh + 368640;
  u16* WFPh = WOPl + 368640;              // 384*768
  u16* WFPl = WFPh + 294912;
  u16* QKh  = WFPl + 294912;              // 1024*384
  u16* QKl  = QKh  + 393216;
  u16* VVh  = QKl  + 393216;              // 1024*480
  u16* VVl  = VVh  + 491520;
  u16* ATBh = VVl  + 491520;              // 2*512*512
  u16* ATBl = ATBh + 524288;
  u16* SRh  = ATBl + 524288;              // 1024*480
  u16* SRl  = SRh  + 491520;
  u16* PRh  = SRl  + 491520;              // 1024*768
  u16* PRl  = PRh  + 786432;
  float* QPf  = (float*)(PRl + 786432);   // 1024*144 f32
  float* ATTf = QPf + 147456;             // 2*512*512 f32

  prep_kernel<<<948, 256, 0, stream>>>(hidden, W_qk, W_vs, W_pv, W_pqk, W_so, W_po, W_fp,
                                       Hhi, Hlo, WINh, WINl, WOPh, WOPl, WFPh, WFPl);
  k_input<<<dim3(21, 16), 256, 0, stream>>>(Hhi, Hlo, WINh, WINl,
                                            b_qk, b_vs, b_pv, b_pqk,
                                            QKh, QKl, VVh, VVl, QPf);
  point_logits<<<dim3(16, 16, 2), 256, 0, stream>>>(QPf, ATTf);
  k_qk<<<dim3(8, 8, 2), 256, 0, stream>>>(QKh, QKl, ATTf);
  softmax_kernel<<<1024, 256, 0, stream>>>(ATTf, ATBh, ATBl);
  k_pv<<<dim3(10, 8, 2), 256, 0, stream>>>(ATBh, ATBl, VVh, VVl, SRh, SRl);
  k_outproj<<<dim3(16, 16), 256, 0, stream>>>(SRh, SRl, WOPh, WOPl, b_so, b_po, PRh, PRl);
  k_final<<<dim3(8, 16), 256, 0, stream>>>(PRh, PRl, WFPh, WFPl, b_fp, out_res);
  delta_kernel<<<1024, 128, 0, stream>>>(PRh, PRl, xyz, out_xyz);
}